// Round 1
// baseline (297.596 us; speedup 1.0000x reference)
//
#include <hip/hip_runtime.h>
#include <hip/hip_cooperative_groups.h>
#include <math.h>

#define NCLS 19
#define DIM  128
#define CD   (NCLS * DIM)   // 2432 floats
#define WPB  8              // waves per block in fused kernel (512 threads)
#define NBLK 256
#define NTHR 512
#define NWAVES (NBLK * WPB) // 2048 waves grid-wide
#define NRP  32             // pairs held in registers per wave (128 VGPRs)

typedef float f32x4 __attribute__((ext_vector_type(4)));

// Nontemporal float4 load: stream past L2/L3 (held data is never re-read).
__device__ __forceinline__ float4 ntload4(const float4* p) {
    f32x4 r = __builtin_nontemporal_load((const f32x4*)p);
    return make_float4(r.x, r.y, r.z, r.w);
}

// 32-lane-group sum via DPP on the VALU pipe. Valid in lanes 31 and 63.
template <int CTRL, int RMASK>
__device__ __forceinline__ float dpp_add(float x) {
    int t = __builtin_amdgcn_update_dpp(0, __builtin_bit_cast(int, x),
                                        CTRL, RMASK, 0xf, true);
    return x + __builtin_bit_cast(float, t);
}
__device__ __forceinline__ float reduce32_dpp(float x) {
    x = dpp_add<0x111, 0xf>(x);   // row_shr:1
    x = dpp_add<0x112, 0xf>(x);   // row_shr:2
    x = dpp_add<0x114, 0xf>(x);   // row_shr:4
    x = dpp_add<0x118, 0xf>(x);   // row_shr:8  -> lane15/31/47/63
    x = dpp_add<0x142, 0xa>(x);   // row_bcast15 -> lanes 31/63 hold 32-sums
    return x;
}

// Per-wave private-table pair accumulation (proven baseline structure).
__device__ __forceinline__ void proc_pair(float* __restrict__ tbl,
                                          int* __restrict__ cnt,
                                          float4 v, int ca, int cb,
                                          int lane, int l31) {
    if (ca == cb) {
        v.x += __shfl_xor(v.x, 32, 64);
        v.y += __shfl_xor(v.y, 32, 64);
        v.z += __shfl_xor(v.z, 32, 64);
        v.w += __shfl_xor(v.w, 32, 64);
        float4* q = (float4*)&tbl[ca * DIM + l31 * 4];
        float4 a = *q;
        a.x += v.x; a.y += v.y; a.z += v.z; a.w += v.w;
        *q = a;                       // both halves write identical values
        if (lane == 0) cnt[ca] += 2;
    } else {
        int c = (lane >= 32) ? cb : ca;
        float4* q = (float4*)&tbl[c * DIM + l31 * 4];
        float4 a = *q;
        a.x += v.x; a.y += v.y; a.z += v.z; a.w += v.w;
        *q = a;                       // halves hit different class rows
        if (lane == 0)  cnt[ca]++;
        if (lane == 32) cnt[cb]++;
    }
}

// Fused cooperative kernel: phase 1 accumulates class sums while holding half
// the input in VGPRs; grid sync; phase 2 computes distances — the held half
// from registers (zero global re-read), the streamed half re-read (L3-warm).
__global__ __launch_bounds__(NTHR, 2)
void k_fused(const float4* __restrict__ in4, const int* __restrict__ tgt,
             float* __restrict__ gsums, int* __restrict__ gcounts,
             float* __restrict__ out, int npair, float inv_n) {
    __shared__ __align__(16) float ls[WPB * CD];    // 77824 B
    __shared__ int   lcnt[WPB * NCLS];
    __shared__ __align__(16) float lcent[CD];       // 9728 B
    __shared__ float red[NTHR];

    const int tid  = threadIdx.x;
    const int w    = tid >> 6;
    const int lane = tid & 63;
    const int l31  = lane & 31;
    float* tbl = &ls[w * CD];
    int*   cnt = &lcnt[w * NCLS];
    const int g = blockIdx.x * WPB + w;             // global wave id, 0..2047

    for (int i = tid; i < WPB * CD; i += NTHR) ls[i] = 0.0f;
    for (int i = tid; i < WPB * NCLS; i += NTHR) lcnt[i] = 0;
    __syncthreads();

    const int hstop = (npair >= NRP * NWAVES) ? NRP * NWAVES : 0;
    const bool full = hstop != 0;

    // ---- Phase 1a: held pairs (nt loads, kept in registers) ----
    float4 hold[NRP];                               // static indices only
    if (full) {
        #pragma unroll
        for (int k = 0; k < NRP; k += 4) {
            const int p0 = (k + 0) * NWAVES + g;
            const int p1 = (k + 1) * NWAVES + g;
            const int p2 = (k + 2) * NWAVES + g;
            const int p3 = (k + 3) * NWAVES + g;
            float4 v0 = ntload4(&in4[(size_t)p0 * 64 + lane]);
            float4 v1 = ntload4(&in4[(size_t)p1 * 64 + lane]);
            float4 v2 = ntload4(&in4[(size_t)p2 * 64 + lane]);
            float4 v3 = ntload4(&in4[(size_t)p3 * 64 + lane]);
            hold[k + 0] = v0; hold[k + 1] = v1;
            hold[k + 2] = v2; hold[k + 3] = v3;
            int a0 = tgt[2 * p0];  int b0 = tgt[2 * p0 + 1];
            int a1 = tgt[2 * p1];  int b1 = tgt[2 * p1 + 1];
            int a2 = tgt[2 * p2];  int b2 = tgt[2 * p2 + 1];
            int a3 = tgt[2 * p3];  int b3 = tgt[2 * p3 + 1];
            proc_pair(tbl, cnt, v0, a0, b0, lane, l31);
            proc_pair(tbl, cnt, v1, a1, b1, lane, l31);
            proc_pair(tbl, cnt, v2, a2, b2, lane, l31);
            proc_pair(tbl, cnt, v3, a3, b3, lane, l31);
        }
    }

    // ---- Phase 1b: streamed pairs (cached loads -> L3 keeps them warm) ----
    int p = hstop + g;
    for (; p + 3 * NWAVES < npair; p += 4 * NWAVES) {
        float4 v0 = in4[(size_t)(p             ) * 64 + lane];
        float4 v1 = in4[(size_t)(p +     NWAVES) * 64 + lane];
        float4 v2 = in4[(size_t)(p + 2 * NWAVES) * 64 + lane];
        float4 v3 = in4[(size_t)(p + 3 * NWAVES) * 64 + lane];
        int a0 = tgt[2 * p];                  int b0 = tgt[2 * p + 1];
        int a1 = tgt[2 * (p + NWAVES)];       int b1 = tgt[2 * (p + NWAVES) + 1];
        int a2 = tgt[2 * (p + 2 * NWAVES)];   int b2 = tgt[2 * (p + 2 * NWAVES) + 1];
        int a3 = tgt[2 * (p + 3 * NWAVES)];   int b3 = tgt[2 * (p + 3 * NWAVES) + 1];
        proc_pair(tbl, cnt, v0, a0, b0, lane, l31);
        proc_pair(tbl, cnt, v1, a1, b1, lane, l31);
        proc_pair(tbl, cnt, v2, a2, b2, lane, l31);
        proc_pair(tbl, cnt, v3, a3, b3, lane, l31);
    }
    for (; p < npair; p += NWAVES) {
        float4 v = in4[(size_t)p * 64 + lane];
        int ca = tgt[2 * p];
        int cb = tgt[2 * p + 1];
        proc_pair(tbl, cnt, v, ca, cb, lane, l31);
    }
    __syncthreads();

    // ---- Cross-wave reduce -> device-scope atomics ----
    for (int i = tid; i < CD; i += NTHR) {
        float s = 0.0f;
        #pragma unroll
        for (int ww = 0; ww < WPB; ww++) s += ls[ww * CD + i];
        unsafeAtomicAdd(&gsums[i], s);
    }
    if (tid < NCLS) {
        int s = 0;
        #pragma unroll
        for (int ww = 0; ww < WPB; ww++) s += lcnt[ww * NCLS + tid];
        atomicAdd(&gcounts[tid], s);
    }
    __threadfence();
    cooperative_groups::this_grid().sync();

    // ---- Centers to LDS ----
    for (int i = tid; i < CD; i += NTHR)
        lcent[i] = gsums[i] / (float)gcounts[i >> 7];
    __syncthreads();

    float acc = 0.0f;

    // ---- Phase 2a: held pairs, zero global input traffic ----
    if (full) {
        #pragma unroll
        for (int k = 0; k < NRP; k++) {
            const int pk = k * NWAVES + g;
            const int2 cc = *(const int2*)&tgt[2 * pk];
            const int c = (lane >= 32) ? cc.y : cc.x;
            const float4 e = *(const float4*)&lcent[c * DIM + l31 * 4];
            const float4 v = hold[k];
            float dx = v.x - e.x, dy = v.y - e.y;
            float dz = v.z - e.z, dw = v.w - e.w;
            float d = dx * dx + dy * dy + dz * dz + dw * dw;
            d = reduce32_dpp(d);
            if (l31 == 31) acc += sqrtf(d);   // lanes 31 & 63: rows 2p, 2p+1
        }
    }

    // ---- Phase 2b: streamed pairs re-read (cached; mostly L3-resident) ----
    int q = hstop + g;
    for (; q + NWAVES < npair; q += 2 * NWAVES) {
        float4 va = in4[(size_t)q * 64 + lane];
        float4 vb = in4[(size_t)(q + NWAVES) * 64 + lane];
        int2 c2a = *(const int2*)&tgt[2 * q];
        int2 c2b = *(const int2*)&tgt[2 * (q + NWAVES)];
        int ca = (lane >= 32) ? c2a.y : c2a.x;
        int cb = (lane >= 32) ? c2b.y : c2b.x;
        float4 ea = *(const float4*)&lcent[ca * DIM + l31 * 4];
        float4 eb = *(const float4*)&lcent[cb * DIM + l31 * 4];
        float dx, dy, dz, dw;
        dx = va.x - ea.x; dy = va.y - ea.y; dz = va.z - ea.z; dw = va.w - ea.w;
        float d0 = dx * dx + dy * dy + dz * dz + dw * dw;
        dx = vb.x - eb.x; dy = vb.y - eb.y; dz = vb.z - eb.z; dw = vb.w - eb.w;
        float d1 = dx * dx + dy * dy + dz * dz + dw * dw;
        d0 = reduce32_dpp(d0);
        d1 = reduce32_dpp(d1);
        if (l31 == 31) acc += sqrtf(d0) + sqrtf(d1);
    }
    for (; q < npair; q += NWAVES) {
        float4 v = in4[(size_t)q * 64 + lane];
        int2 c2 = *(const int2*)&tgt[2 * q];
        int c = (lane >= 32) ? c2.y : c2.x;
        float4 e = *(const float4*)&lcent[c * DIM + l31 * 4];
        float dx = v.x - e.x, dy = v.y - e.y, dz = v.z - e.z, dw = v.w - e.w;
        float d = dx * dx + dy * dy + dz * dz + dw * dw;
        d = reduce32_dpp(d);
        if (l31 == 31) acc += sqrtf(d);
    }

    red[tid] = acc;
    __syncthreads();
    for (int s = NTHR / 2; s > 0; s >>= 1) {
        if (tid < s) red[tid] += red[tid + s];
        __syncthreads();
    }
    if (tid == 0) unsafeAtomicAdd(out, red[0] * inv_n);
}

// ---------------- Fallback path (previous best, 2 kernels) ----------------
#define AWPB 16
__global__ __launch_bounds__(1024) void k_accum(const float4* __restrict__ in4,
                                                const int* __restrict__ tgt,
                                                float* __restrict__ gsums,
                                                int* __restrict__ gcounts,
                                                int npair) {
    __shared__ __align__(16) float ls[AWPB * CD];
    __shared__ int lcnt[AWPB * NCLS];
    const int tid  = threadIdx.x;
    const int w    = tid >> 6;
    const int lane = tid & 63;
    const int l31  = lane & 31;
    float* tbl = &ls[w * CD];
    int*   cnt = &lcnt[w * NCLS];

    for (int i = tid; i < AWPB * CD; i += 1024) ls[i] = 0.0f;
    for (int i = tid; i < AWPB * NCLS; i += 1024) lcnt[i] = 0;
    __syncthreads();

    const int stride = gridDim.x * AWPB;
    int p = blockIdx.x * AWPB + w;
    for (; p < npair; p += stride) {
        float4 v = ntload4(&in4[(size_t)p * 64 + lane]);
        int ca = tgt[2 * p];
        int cb = tgt[2 * p + 1];
        proc_pair(tbl, cnt, v, ca, cb, lane, l31);
    }
    __syncthreads();

    for (int i = tid; i < CD; i += 1024) {
        float s = 0.0f;
        #pragma unroll
        for (int ww = 0; ww < AWPB; ww++) s += ls[ww * CD + i];
        unsafeAtomicAdd(&gsums[i], s);
    }
    if (tid < NCLS) {
        int s = 0;
        #pragma unroll
        for (int ww = 0; ww < AWPB; ww++) s += lcnt[ww * NCLS + tid];
        atomicAdd(&gcounts[tid], s);
    }
}

__global__ __launch_bounds__(256) void k_dist(const float4* __restrict__ in4,
                                              const int* __restrict__ tgt,
                                              const float* __restrict__ gsums,
                                              const int* __restrict__ gcounts,
                                              float* __restrict__ out,
                                              int n, float inv_n) {
    __shared__ __align__(16) float lcent[CD];
    __shared__ float red[256];
    const int tid = threadIdx.x;
    for (int i = tid; i < CD; i += 256)
        lcent[i] = gsums[i] / (float)gcounts[i >> 7];
    __syncthreads();

    const int l32 = tid & 31;
    const int gg  = tid >> 5;
    const int stride = gridDim.x * 8;
    float acc = 0.0f;
    for (int row = blockIdx.x * 8 + gg; row < n; row += stride) {
        float4 v = ntload4(&in4[(size_t)row * 32 + l32]);
        int c = tgt[row];
        float4 ce = *(const float4*)&lcent[c * DIM + l32 * 4];
        float dx = v.x - ce.x, dy = v.y - ce.y, dz = v.z - ce.z, dw = v.w - ce.w;
        float d2 = dx * dx + dy * dy + dz * dz + dw * dw;
        d2 = reduce32_dpp(d2);
        if (l32 == 31) acc += sqrtf(d2);
    }
    red[tid] = acc;
    __syncthreads();
    for (int s = 128; s > 0; s >>= 1) {
        if (tid < s) red[tid] += red[tid + s];
        __syncthreads();
    }
    if (tid == 0) unsafeAtomicAdd(out, red[0] * inv_n);
}

extern "C" void kernel_launch(void* const* d_in, const int* in_sizes, int n_in,
                              void* d_out, int out_size, void* d_ws, size_t ws_size,
                              hipStream_t stream) {
    const float* in  = (const float*)d_in[0];
    const int*   tgt = (const int*)d_in[1];
    const int n = in_sizes[0] / DIM;       // 262144

    float* gsums   = (float*)d_ws;             // [19][128]
    int*   gcounts = (int*)(gsums + CD);       // [19]
    float* out     = (float*)d_out;

    (void)hipMemsetAsync(d_ws, 0, CD * sizeof(float) + NCLS * sizeof(int), stream);
    (void)hipMemsetAsync(d_out, 0, sizeof(float), stream);

    const float4* in4 = (const float4*)in;
    int   npair = n / 2;
    float inv_n = 1.0f / (float)n;
    void* args[] = {(void*)&in4, (void*)&tgt, (void*)&gsums, (void*)&gcounts,
                    (void*)&out, (void*)&npair, (void*)&inv_n};
    hipError_t rc = hipLaunchCooperativeKernel((const void*)k_fused, dim3(NBLK),
                                               dim3(NTHR), args, 0, stream);
    if (rc != hipSuccess) {
        // Cooperative launch unavailable (e.g. under capture) — previous best.
        k_accum<<<256, 1024, 0, stream>>>(in4, tgt, gsums, gcounts, npair);
        k_dist<<<1024, 256, 0, stream>>>(in4, tgt, gsums, gcounts, out, n, inv_n);
    }
}

// Round 2
// 230.127 us; speedup vs baseline: 1.2932x; 1.2932x over previous
//
#include <hip/hip_runtime.h>
#include <math.h>

#define NCLS 19
#define DIM  128
#define CD   (NCLS * DIM)   // 2432 floats
#define WPB  8              // waves per block (512 threads)
#define NBLK 256            // == CU count; LDS forces 1 block/CU -> co-resident
#define NTHR 512
#define NWAVES (NBLK * WPB) // 2048 waves grid-wide
#define NRP  32             // pairs held in registers per wave (128 VGPRs)

typedef float f32x4 __attribute__((ext_vector_type(4)));

// Nontemporal float4 load: held data is consumed once from HBM and then lives
// in VGPRs -> bypass L2/L3 allocation so the streamed half stays resident.
__device__ __forceinline__ float4 ntload4(const float4* p) {
    f32x4 r = __builtin_nontemporal_load((const f32x4*)p);
    return make_float4(r.x, r.y, r.z, r.w);
}

// 32-lane-group sum via DPP on the VALU pipe. Valid in lanes 31 and 63.
template <int CTRL, int RMASK>
__device__ __forceinline__ float dpp_add(float x) {
    int t = __builtin_amdgcn_update_dpp(0, __builtin_bit_cast(int, x),
                                        CTRL, RMASK, 0xf, true);
    return x + __builtin_bit_cast(float, t);
}
__device__ __forceinline__ float reduce32_dpp(float x) {
    x = dpp_add<0x111, 0xf>(x);   // row_shr:1
    x = dpp_add<0x112, 0xf>(x);   // row_shr:2
    x = dpp_add<0x114, 0xf>(x);   // row_shr:4
    x = dpp_add<0x118, 0xf>(x);   // row_shr:8  -> lane15/31/47/63
    x = dpp_add<0x142, 0xa>(x);   // row_bcast15 -> lanes 31/63 hold 32-sums
    return x;
}

// Per-wave private-table pair accumulation (proven baseline structure).
__device__ __forceinline__ void proc_pair(float* __restrict__ tbl,
                                          int* __restrict__ cnt,
                                          float4 v, int ca, int cb,
                                          int lane, int l31) {
    if (ca == cb) {
        v.x += __shfl_xor(v.x, 32, 64);
        v.y += __shfl_xor(v.y, 32, 64);
        v.z += __shfl_xor(v.z, 32, 64);
        v.w += __shfl_xor(v.w, 32, 64);
        float4* q = (float4*)&tbl[ca * DIM + l31 * 4];
        float4 a = *q;
        a.x += v.x; a.y += v.y; a.z += v.z; a.w += v.w;
        *q = a;                       // both halves write identical values
        if (lane == 0) cnt[ca] += 2;
    } else {
        int c = (lane >= 32) ? cb : ca;
        float4* q = (float4*)&tbl[c * DIM + l31 * 4];
        float4 a = *q;
        a.x += v.x; a.y += v.y; a.z += v.z; a.w += v.w;
        *q = a;                       // halves hit different class rows
        if (lane == 0)  cnt[ca]++;
        if (lane == 32) cnt[cb]++;
    }
}

// Fused kernel, NORMAL launch (graph-capturable). Grid-wide sync via a
// device-scope atomic barrier — safe because 90.2 KB LDS caps occupancy at
// 1 block/CU and grid == 256 == CU count, so all blocks are co-resident
// (co-residency at this shape was proven by last round's cooperative launch).
__global__ __launch_bounds__(NTHR, 2)
void k_fused(const float4* __restrict__ in4, const int* __restrict__ tgt,
             float* __restrict__ gsums, int* __restrict__ gcounts,
             int* __restrict__ bar, float* __restrict__ out,
             int npair, float inv_n) {
    __shared__ __align__(16) float ls[WPB * CD];    // 77824 B
    __shared__ int   lcnt[WPB * NCLS];
    __shared__ __align__(16) float lcent[CD];       // 9728 B
    __shared__ float red[NTHR];

    const int tid  = threadIdx.x;
    const int w    = tid >> 6;
    const int lane = tid & 63;
    const int l31  = lane & 31;
    float* tbl = &ls[w * CD];
    int*   cnt = &lcnt[w * NCLS];
    const int g = blockIdx.x * WPB + w;             // global wave id, 0..2047

    for (int i = tid; i < WPB * CD; i += NTHR) ls[i] = 0.0f;
    for (int i = tid; i < WPB * NCLS; i += NTHR) lcnt[i] = 0;
    __syncthreads();

    const int hstop = (npair >= NRP * NWAVES) ? NRP * NWAVES : 0;
    const bool full = hstop != 0;

    // ---- Phase 1a: held pairs (nt loads, kept in registers) ----
    float4 hold[NRP];                               // static indices only
    if (full) {
        #pragma unroll
        for (int k = 0; k < NRP; k += 4) {
            const int p0 = (k + 0) * NWAVES + g;
            const int p1 = (k + 1) * NWAVES + g;
            const int p2 = (k + 2) * NWAVES + g;
            const int p3 = (k + 3) * NWAVES + g;
            float4 v0 = ntload4(&in4[(size_t)p0 * 64 + lane]);
            float4 v1 = ntload4(&in4[(size_t)p1 * 64 + lane]);
            float4 v2 = ntload4(&in4[(size_t)p2 * 64 + lane]);
            float4 v3 = ntload4(&in4[(size_t)p3 * 64 + lane]);
            hold[k + 0] = v0; hold[k + 1] = v1;
            hold[k + 2] = v2; hold[k + 3] = v3;
            int a0 = tgt[2 * p0];  int b0 = tgt[2 * p0 + 1];
            int a1 = tgt[2 * p1];  int b1 = tgt[2 * p1 + 1];
            int a2 = tgt[2 * p2];  int b2 = tgt[2 * p2 + 1];
            int a3 = tgt[2 * p3];  int b3 = tgt[2 * p3 + 1];
            proc_pair(tbl, cnt, v0, a0, b0, lane, l31);
            proc_pair(tbl, cnt, v1, a1, b1, lane, l31);
            proc_pair(tbl, cnt, v2, a2, b2, lane, l31);
            proc_pair(tbl, cnt, v3, a3, b3, lane, l31);
        }
        // ANCHOR: make every held float asm-produced so the compiler cannot
        // rematerialize the loads in phase 2 (round-1 failure: VGPR_Count=96
        // proved `hold` was dropped and the input was read twice anyway).
        #pragma unroll
        for (int k = 0; k < NRP; k++) {
            asm volatile("" : "+v"(hold[k].x), "+v"(hold[k].y),
                              "+v"(hold[k].z), "+v"(hold[k].w));
        }
    }

    // ---- Phase 1b: streamed pairs (cached loads -> L3 keeps them warm) ----
    int p = hstop + g;
    for (; p + 3 * NWAVES < npair; p += 4 * NWAVES) {
        float4 v0 = in4[(size_t)(p             ) * 64 + lane];
        float4 v1 = in4[(size_t)(p +     NWAVES) * 64 + lane];
        float4 v2 = in4[(size_t)(p + 2 * NWAVES) * 64 + lane];
        float4 v3 = in4[(size_t)(p + 3 * NWAVES) * 64 + lane];
        int a0 = tgt[2 * p];                  int b0 = tgt[2 * p + 1];
        int a1 = tgt[2 * (p + NWAVES)];       int b1 = tgt[2 * (p + NWAVES) + 1];
        int a2 = tgt[2 * (p + 2 * NWAVES)];   int b2 = tgt[2 * (p + 2 * NWAVES) + 1];
        int a3 = tgt[2 * (p + 3 * NWAVES)];   int b3 = tgt[2 * (p + 3 * NWAVES) + 1];
        proc_pair(tbl, cnt, v0, a0, b0, lane, l31);
        proc_pair(tbl, cnt, v1, a1, b1, lane, l31);
        proc_pair(tbl, cnt, v2, a2, b2, lane, l31);
        proc_pair(tbl, cnt, v3, a3, b3, lane, l31);
    }
    for (; p < npair; p += NWAVES) {
        float4 v = in4[(size_t)p * 64 + lane];
        int ca = tgt[2 * p];
        int cb = tgt[2 * p + 1];
        proc_pair(tbl, cnt, v, ca, cb, lane, l31);
    }
    __syncthreads();

    // ---- Cross-wave reduce -> device-scope atomics ----
    for (int i = tid; i < CD; i += NTHR) {
        float s = 0.0f;
        #pragma unroll
        for (int ww = 0; ww < WPB; ww++) s += ls[ww * CD + i];
        unsafeAtomicAdd(&gsums[i], s);
    }
    if (tid < NCLS) {
        int s = 0;
        #pragma unroll
        for (int ww = 0; ww < WPB; ww++) s += lcnt[ww * NCLS + tid];
        atomicAdd(&gcounts[tid], s);
    }

    // ---- Software grid barrier (device-scope) ----
    __syncthreads();                   // all block atomics issued
    if (tid == 0) {
        __hip_atomic_fetch_add(bar, 1, __ATOMIC_ACQ_REL,
                               __HIP_MEMORY_SCOPE_AGENT);
        while (__hip_atomic_load(bar, __ATOMIC_ACQUIRE,
                                 __HIP_MEMORY_SCOPE_AGENT) < NBLK) {
            __builtin_amdgcn_s_sleep(8);
        }
    }
    __syncthreads();

    // ---- Centers to LDS (agent-scope loads: cross-XCD L2 not coherent) ----
    for (int i = tid; i < CD; i += NTHR) {
        float s = __hip_atomic_load(&gsums[i], __ATOMIC_RELAXED,
                                    __HIP_MEMORY_SCOPE_AGENT);
        int   c = __hip_atomic_load(&gcounts[i >> 7], __ATOMIC_RELAXED,
                                    __HIP_MEMORY_SCOPE_AGENT);
        lcent[i] = s / (float)c;
    }
    __syncthreads();

    float acc = 0.0f;

    // ---- Phase 2a: held pairs, zero global input traffic ----
    if (full) {
        #pragma unroll
        for (int k = 0; k < NRP; k++) {
            const int pk = k * NWAVES + g;
            const int2 cc = *(const int2*)&tgt[2 * pk];
            const int c = (lane >= 32) ? cc.y : cc.x;
            const float4 e = *(const float4*)&lcent[c * DIM + l31 * 4];
            const float4 v = hold[k];
            float dx = v.x - e.x, dy = v.y - e.y;
            float dz = v.z - e.z, dw = v.w - e.w;
            float d = dx * dx + dy * dy + dz * dz + dw * dw;
            d = reduce32_dpp(d);
            if (l31 == 31) acc += sqrtf(d);   // lanes 31 & 63: rows 2p, 2p+1
        }
    }

    // ---- Phase 2b: streamed pairs re-read (L3-resident) ----
    int q = hstop + g;
    for (; q + NWAVES < npair; q += 2 * NWAVES) {
        float4 va = in4[(size_t)q * 64 + lane];
        float4 vb = in4[(size_t)(q + NWAVES) * 64 + lane];
        int2 c2a = *(const int2*)&tgt[2 * q];
        int2 c2b = *(const int2*)&tgt[2 * (q + NWAVES)];
        int ca = (lane >= 32) ? c2a.y : c2a.x;
        int cb = (lane >= 32) ? c2b.y : c2b.x;
        float4 ea = *(const float4*)&lcent[ca * DIM + l31 * 4];
        float4 eb = *(const float4*)&lcent[cb * DIM + l31 * 4];
        float dx, dy, dz, dw;
        dx = va.x - ea.x; dy = va.y - ea.y; dz = va.z - ea.z; dw = va.w - ea.w;
        float d0 = dx * dx + dy * dy + dz * dz + dw * dw;
        dx = vb.x - eb.x; dy = vb.y - eb.y; dz = vb.z - eb.z; dw = vb.w - eb.w;
        float d1 = dx * dx + dy * dy + dz * dz + dw * dw;
        d0 = reduce32_dpp(d0);
        d1 = reduce32_dpp(d1);
        if (l31 == 31) acc += sqrtf(d0) + sqrtf(d1);
    }
    for (; q < npair; q += NWAVES) {
        float4 v = in4[(size_t)q * 64 + lane];
        int2 c2 = *(const int2*)&tgt[2 * q];
        int c = (lane >= 32) ? c2.y : c2.x;
        float4 e = *(const float4*)&lcent[c * DIM + l31 * 4];
        float dx = v.x - e.x, dy = v.y - e.y, dz = v.z - e.z, dw = v.w - e.w;
        float d = dx * dx + dy * dy + dz * dz + dw * dw;
        d = reduce32_dpp(d);
        if (l31 == 31) acc += sqrtf(d);
    }

    red[tid] = acc;
    __syncthreads();
    for (int s = NTHR / 2; s > 0; s >>= 1) {
        if (tid < s) red[tid] += red[tid + s];
        __syncthreads();
    }
    if (tid == 0) unsafeAtomicAdd(out, red[0] * inv_n);
}

extern "C" void kernel_launch(void* const* d_in, const int* in_sizes, int n_in,
                              void* d_out, int out_size, void* d_ws, size_t ws_size,
                              hipStream_t stream) {
    const float* in  = (const float*)d_in[0];
    const int*   tgt = (const int*)d_in[1];
    const int n = in_sizes[0] / DIM;       // 262144

    float* gsums   = (float*)d_ws;             // [19][128]
    int*   gcounts = (int*)(gsums + CD);       // [19]
    int*   bar     = gcounts + NCLS;           // grid-barrier counter
    float* out     = (float*)d_out;

    // Harness re-poisons d_out/d_ws to 0xAA before every timed call; zero the
    // live workspace region (sums, counts, barrier) and the output.
    (void)hipMemsetAsync(d_ws, 0, (CD + NCLS + 1) * sizeof(float), stream);
    (void)hipMemsetAsync(d_out, 0, sizeof(float), stream);

    const float4* in4 = (const float4*)in;
    k_fused<<<NBLK, NTHR, 0, stream>>>(in4, tgt, gsums, gcounts, bar,
                                       out, n / 2, 1.0f / (float)n);
}